// Round 5
// baseline (144.578 us; speedup 1.0000x reference)
//
#include <hip/hip_runtime.h>
#include <hip/hip_bf16.h>

#define NN 50000
#define NE 625000
#define CH 128
// CSR row block: 32 uints = 128B = [u32 deg][62 ushort slots]; max degree ~38 << 62
#define RSTR 32
// counting-sort geometry: group = row >> 8 -> 196 groups of 256 rows
#define NG 196
#define NBIN 512           // sort blocks in pass A (deterministic, no device atomics)
#define EPB 1221           // edges per sort block (512*1221 = 625152 >= NE)

typedef __attribute__((ext_vector_type(8))) short short8;
typedef __attribute__((ext_vector_type(4))) float floatx4;

__device__ __forceinline__ ushort f2bf(float v) {
    __hip_bfloat16 h = __float2bfloat16(v);
    return *(ushort*)&h;
}
__device__ __forceinline__ float bf2f(uint u) {
    return __uint_as_float(u << 16);
}

// ---------------- fused prep ----------------
// blocks [0,512):      edge sort pass A: per-block group-sort into OWN gseg
//                      region (coalesced identity copy-out, zero device atomics)
// blocks [512,6762):   cast x -> bf16 (4 f32/thr)
// blocks [6762,6826):  W -> bf16 hi/lo split (+ zero row xb[NN] once)
__global__ __launch_bounds__(256) void k_prep(const float* __restrict__ x,
                                              ushort* __restrict__ xb,
                                              const float* __restrict__ W,
                                              ushort* __restrict__ whi,
                                              ushort* __restrict__ wlo,
                                              const int* __restrict__ row,
                                              const int* __restrict__ col,
                                              uint* __restrict__ runtbl,
                                              uint* __restrict__ gseg) {
    __shared__ uint cnt[NG];   // per-group count (atomic rank source)
    __shared__ uint sc[NG];    // block-local exclusive scan
    __shared__ uint ss[256];   // scan workspace
    __shared__ uint pk[EPB];   // packed edges, ordered by group

    int b = blockIdx.x;
    int t = threadIdx.x;
    if (b < NBIN) {
        int e0 = b * EPB;
        int n = NE - e0; if (n > EPB) n = EPB;     // last block: 1069

        for (int i = t; i < NG; i += 256) cnt[i] = 0;
        __syncthreads();

        // load up to 5 edges/thread, coalesced
        int r[5], c[5], g[5];
        uint rk[5];
#pragma unroll
        for (int j = 0; j < 5; ++j) {
            int i = t + j * 256;
            int idx = (i < n) ? (e0 + i) : e0;     // clamped read
            r[j] = row[idx];
            c[j] = col[idx];
        }
#pragma unroll
        for (int j = 0; j < 5; ++j) {
            g[j] = r[j] >> 8;
            if (t + j * 256 < n) rk[j] = atomicAdd(&cnt[g[j]], 1u);
        }
        __syncthreads();

        // exclusive scan of cnt over 196 (padded to 256), Hillis-Steele
        ss[t] = (t < NG) ? cnt[t] : 0u;
        __syncthreads();
        for (int off = 1; off < 256; off <<= 1) {
            uint add = (t >= off) ? ss[t - off] : 0u;
            __syncthreads();
            ss[t] += add;
            __syncthreads();
        }
        if (t < NG) {
            sc[t] = ss[t] - cnt[t];
            // publish run descriptor: [g][b] = (local_start<<12)|len
            runtbl[(size_t)t * NBIN + b] = (sc[t] << 12) | cnt[t];
        }
        __syncthreads();

        // place edges into block-local group-ordered buffer (LDS scatter)
#pragma unroll
        for (int j = 0; j < 5; ++j) {
            if (t + j * 256 < n) {
                uint pos = sc[g[j]] + rk[j];
                pk[pos] = ((uint)(r[j] & 255) << 16) | (uint)(c[j] & 0xffff);
            }
        }
        __syncthreads();

        // identity copy-out: fully coalesced into this block's own region
        for (int i = t; i < n; i += 256)
            gseg[e0 + i] = pk[i];
    } else if (b < 6762) {
        int i = ((b - 512) * 256 + t) * 4;         // 6,400,000 elems exactly
        float4 v = *(const float4*)(x + i);
        ushort4 o;
        o.x = f2bf(v.x); o.y = f2bf(v.y); o.z = f2bf(v.z); o.w = f2bf(v.w);
        *(ushort4*)(xb + i) = o;
    } else {
        int i = (b - 6762) * 256 + t;              // 16384 elems exactly
        float v = W[i];
        ushort hh = f2bf(v);
        whi[i] = hh;
        wlo[i] = f2bf(v - bf2f((uint)hh));
        if (b == 6762 && t < 64)                   // dedicated zero row for pad slots
            ((uint*)(xb + (size_t)NN * CH))[t] = 0u;
    }
}

// ---------------- pass B: build CSR + deg/nrm + PRE-SCALE xb rows by dis ----------------
// 2 blocks per group; block handles 128 of the group's 256 rows.
// After binning, scales xb[row] *= dis[row] in place (source-side norm),
// so the aggregation loop needs NO per-neighbor norm at all.
__global__ __launch_bounds__(256) void k_csr(const uint* __restrict__ gseg,
                                             const uint* __restrict__ runtbl,
                                             uint* __restrict__ csr,
                                             int* __restrict__ deg_c,
                                             float* __restrict__ nrm,
                                             ushort* __restrict__ xb) {
    __shared__ ushort slots[128][62];
    __shared__ uint dcnt[128];
    __shared__ float sdis[128];
    __shared__ uint rt[NBIN];
    int g = blockIdx.x >> 1;
    int q = blockIdx.x & 1;
    int t = threadIdx.x;

    if (t < 128) dcnt[t] = 0;
    for (int i = t; i < NBIN; i += 256)
        rt[i] = runtbl[(size_t)g * NBIN + i];
    __syncthreads();

#pragma unroll
    for (int rep = 0; rep < NBIN / 256; ++rep) {
        int bb = t + rep * 256;
        uint d = rt[bb];
        uint s = d >> 12, len = d & 0xFFFu;
        const uint* p = gseg + (size_t)bb * EPB + s;
        for (uint k = 0; k < len; ++k) {
            uint e = p[k];
            int rl = (int)(e >> 16);               // row & 255
            if ((rl >> 7) == q) {
                int r7 = rl & 127;
                uint kk = atomicAdd(&dcnt[r7], 1u);
                if (kk < 62) slots[r7][kk] = (ushort)(e & 0xffff);
            }
        }
    }
    __syncthreads();

    int row0 = g * 256 + q * 128;
    // deg/nrm/dis for this block's 128 rows
    if (t < 128) {
        int rr = row0 + t;
        int d = (int)dcnt[t];
        float dis = (d > 0) ? rsqrtf((float)d) : 0.0f;
        sdis[t] = dis;
        if (rr < NN) {
            deg_c[rr] = d;
            nrm[rr] = dis;
        }
    }
    // CSR write: 128 rows x 32 uints = 4096 uints, coalesced
    for (int i = t; i < 4096; i += 256) {
        int rl = i >> 5, w = i & 31;
        int rr = row0 + rl;
        if (rr < NN) {
            uint val;
            if (w == 0) val = dcnt[rl];
            else val = (uint)slots[rl][2 * w - 2] | ((uint)slots[rl][2 * w - 1] << 16);
            csr[(size_t)rr * RSTR + w] = val;
        }
    }
    __syncthreads();

    // in-place scale: xb[rr] *= dis[rr]; 128 rows x 64 uints, coalesced
    for (int i = t; i < 128 * 64; i += 256) {
        int rl = i >> 6, w = i & 63;
        int rr = row0 + rl;
        if (rr < NN) {
            uint* p = (uint*)(xb + (size_t)rr * CH);
            uint u = p[w];
            float s = sdis[rl];
            float lo = bf2f(u);                            // low ushort
            float hi = __uint_as_float(u & 0xffff0000u);   // high ushort
            p[w] = (uint)f2bf(lo * s) | ((uint)f2bf(hi * s) << 16);
        }
    }
}

// ---------------- fused aggregation + MFMA GEMM ----------------
// Block owns 32 nodes. Phase 1: each wave sums pre-scaled source rows for
// 8 nodes into an XOR-swizzled LDS A-tile (pure unweighted row-sum: 2
// readlanes/pair, one b64 gather serving TWO rows via lane-half split;
// pad slots read the zero row xb[NN]). Phase 2: 16x16x32 MFMA tile.
__global__ __launch_bounds__(256) void k_aggm(const ushort* __restrict__ xb,
                                              const int* __restrict__ deg_c,
                                              const float* __restrict__ nrm,
                                              const uint* __restrict__ csr,
                                              const ushort* __restrict__ whi,
                                              const ushort* __restrict__ wlo,
                                              const float* __restrict__ bias,
                                              float* __restrict__ out) {
    __shared__ ushort at[32 * 128];                // 8KB, swizzled
    const int wave = threadIdx.x >> 6;
    const int lane = threadIdx.x & 63;
    const int half = lane >> 5;
    const int lq = lane & 31;
    const int m0 = blockIdx.x * 32;
    const int li = (lane < 62) ? lane : 0;

    // ---- phase 1: aggregate nodes m0+wave*8 .. +7 ----
    int node0 = m0 + wave * 8;
    int deg_n = 0; ushort craw_n = 0; float dr_n = 0.0f;
    if (node0 < NN) {
        deg_n  = deg_c[node0];
        craw_n = ((const ushort*)(csr + (size_t)node0 * RSTR))[2 + li];
        dr_n   = nrm[node0];
    }
    for (int s = 0; s < 8; ++s) {
        int node = node0 + s;
        int r = wave * 8 + s;
        if (node >= NN) {                          // zero the tile row (last block only)
            if (half == 0) {
                int byte = (r * 256 + lq * 8) ^ ((r & 7) << 4);
                *(uint2*)((char*)at + byte) = make_uint2(0u, 0u);
            }
            continue;
        }
        int deg = deg_n; ushort craw = craw_n; float dr = dr_n;
        int cli = (lane < deg) ? (int)craw : NN;   // pads -> zero row
        // prefetch next node's metadata under this node's gather loop
        int nxt = node + 1;
        if (s < 7 && nxt < NN) {
            deg_n  = deg_c[nxt];
            craw_n = ((const ushort*)(csr + (size_t)nxt * RSTR))[2 + li];
            dr_n   = nrm[nxt];
        }
        float a0 = 0.f, a1 = 0.f, a2 = 0.f, a3 = 0.f;
        for (int j = 0; j < deg; j += 8) {
#pragma unroll
            for (int up = 0; up < 4; ++up) {
                int i0 = j + 2 * up;               // i0+1 <= 63 always (deg <= 62)
                int cc0 = __builtin_amdgcn_readlane(cli, i0);
                int cc1 = __builtin_amdgcn_readlane(cli, i0 + 1);
                int cc  = half ? cc1 : cc0;
                uint2 v = *(const uint2*)(xb + (size_t)cc * CH + lq * 4);
                a0 += bf2f(v.x);
                a1 += __uint_as_float(v.x & 0xffff0000u);
                a2 += bf2f(v.y);
                a3 += __uint_as_float(v.y & 0xffff0000u);
            }
        }
        a0 += __shfl_xor(a0, 32);
        a1 += __shfl_xor(a1, 32);
        a2 += __shfl_xor(a2, 32);
        a3 += __shfl_xor(a3, 32);
        if (half == 0) {
            uint w0 = (uint)f2bf(a0 * dr) | ((uint)f2bf(a1 * dr) << 16);
            uint w1 = (uint)f2bf(a2 * dr) | ((uint)f2bf(a3 * dr) << 16);
            int byte = (r * 256 + lq * 8) ^ ((r & 7) << 4);
            *(uint2*)((char*)at + byte) = make_uint2(w0, w1);
        }
    }
    __syncthreads();

    // ---- phase 2: GEMM out = A @ (Whi+Wlo)^T + b ----
    const int quad = lane >> 4;
    const int r16 = lane & 15;
    const int nt0 = wave * 2, nt1 = nt0 + 1;
    const ushort* bh0p = whi + (size_t)(nt0 * 16 + r16) * CH + quad * 8;
    const ushort* bl0p = wlo + (size_t)(nt0 * 16 + r16) * CH + quad * 8;
    const ushort* bh1p = whi + (size_t)(nt1 * 16 + r16) * CH + quad * 8;
    const ushort* bl1p = wlo + (size_t)(nt1 * 16 + r16) * CH + quad * 8;

    float b0 = bias[nt0 * 16 + r16];
    float b1 = bias[nt1 * 16 + r16];
    floatx4 acc00 = {b0, b0, b0, b0};
    floatx4 acc01 = {b1, b1, b1, b1};
    floatx4 acc10 = {b0, b0, b0, b0};
    floatx4 acc11 = {b1, b1, b1, b1};

    const int swz = (r16 & 7) << 4;                // (r16+16)&7 == r16&7
#pragma unroll
    for (int kb = 0; kb < 4; ++kb) {
        const int cb = quad * 16 + kb * 64;
        short8 A0 = *(const short8*)((const char*)at + ((r16 * 256 + cb) ^ swz));
        short8 A1 = *(const short8*)((const char*)at + (((r16 + 16) * 256 + cb) ^ swz));
        const int k0 = kb * 32;
        short8 h0 = *(const short8*)(bh0p + k0);
        short8 l0 = *(const short8*)(bl0p + k0);
        short8 h1 = *(const short8*)(bh1p + k0);
        short8 l1 = *(const short8*)(bl1p + k0);
        acc00 = __builtin_amdgcn_mfma_f32_16x16x32_bf16(A0, h0, acc00, 0, 0, 0);
        acc00 = __builtin_amdgcn_mfma_f32_16x16x32_bf16(A0, l0, acc00, 0, 0, 0);
        acc01 = __builtin_amdgcn_mfma_f32_16x16x32_bf16(A0, h1, acc01, 0, 0, 0);
        acc01 = __builtin_amdgcn_mfma_f32_16x16x32_bf16(A0, l1, acc01, 0, 0, 0);
        acc10 = __builtin_amdgcn_mfma_f32_16x16x32_bf16(A1, h0, acc10, 0, 0, 0);
        acc10 = __builtin_amdgcn_mfma_f32_16x16x32_bf16(A1, l0, acc10, 0, 0, 0);
        acc11 = __builtin_amdgcn_mfma_f32_16x16x32_bf16(A1, h1, acc11, 0, 0, 0);
        acc11 = __builtin_amdgcn_mfma_f32_16x16x32_bf16(A1, l1, acc11, 0, 0, 0);
    }

#pragma unroll
    for (int r = 0; r < 4; ++r) {
        int row0 = m0 + quad * 4 + r;
        int row1 = row0 + 16;
        if (row0 < NN) {
            out[(size_t)row0 * CH + nt0 * 16 + r16] = acc00[r];
            out[(size_t)row0 * CH + nt1 * 16 + r16] = acc01[r];
        }
        if (row1 < NN) {
            out[(size_t)row1 * CH + nt0 * 16 + r16] = acc10[r];
            out[(size_t)row1 * CH + nt1 * 16 + r16] = acc11[r];
        }
    }
}

extern "C" void kernel_launch(void* const* d_in, const int* in_sizes, int n_in,
                              void* d_out, int out_size, void* d_ws, size_t ws_size,
                              hipStream_t stream) {
    const float* x = (const float*)d_in[0];
    const int* ei = (const int*)d_in[1]; // [2, NE]: row = ei, col = ei + NE
    const float* W = (const float*)d_in[2];
    const float* b = (const float*)d_in[3];
    float* out = (float*)d_out;

    // ws: [csr NN*32 uint = 6.4MB][deg_c 50176 int][nrm 50176 f32]
    //     [xb (NN+1)*CH u16 (row NN = zero row)][whi 16384 u16][wlo 16384 u16]
    //     [runtbl NG*NBIN uint][gseg NBIN*EPB uint]
    uint* csr = (uint*)d_ws;
    int* deg_c = (int*)(csr + (size_t)NN * RSTR);
    float* nrm = (float*)(deg_c + 50176);
    ushort* xb = (ushort*)(nrm + 50176);
    ushort* whi = xb + (size_t)(NN + 1) * CH;
    ushort* wlo = whi + CH * CH;
    uint* runtbl = (uint*)(wlo + CH * CH);
    uint* gseg = runtbl + (size_t)NG * NBIN;

    k_prep<<<6826, 256, 0, stream>>>(x, xb, W, whi, wlo, ei, ei + NE, runtbl, gseg);
    k_csr<<<NG * 2, 256, 0, stream>>>(gseg, runtbl, csr, deg_c, nrm, xb);
    k_aggm<<<(NN + 31) / 32, 256, 0, stream>>>(xb, deg_c, nrm, csr, whi, wlo, b, out);
}

// Round 6
// 136.778 us; speedup vs baseline: 1.0570x; 1.0570x over previous
//
#include <hip/hip_runtime.h>
#include <hip/hip_bf16.h>

#define NN 50000
#define NE 625000
#define CH 128
// CSR row block: 32 uints = 128B = [u32 deg][62 ushort slots]; max degree ~38 << 62
#define RSTR 32
// counting-sort geometry: group = row >> 8 -> 196 groups of 256 rows
#define NG 196
#define NBIN 512           // sort blocks in pass A (deterministic, no device atomics)
#define EPB 1221           // edges per sort block (512*1221 = 625152 >= NE)

typedef __attribute__((ext_vector_type(8))) short short8;
typedef __attribute__((ext_vector_type(4))) float floatx4;

__device__ __forceinline__ ushort f2bf(float v) {
    __hip_bfloat16 h = __float2bfloat16(v);
    return *(ushort*)&h;
}
__device__ __forceinline__ float bf2f(uint u) {
    return __uint_as_float(u << 16);
}

// ---------------- prep: edge sort + W split (NO cast here anymore) ----------------
// blocks [0,512):    edge sort pass A: per-block group-sort into OWN gseg
//                    region (coalesced identity copy-out, zero device atomics)
// blocks [512,576):  W -> bf16 hi/lo split
__global__ __launch_bounds__(256) void k_prep(const float* __restrict__ W,
                                              ushort* __restrict__ whi,
                                              ushort* __restrict__ wlo,
                                              const int* __restrict__ row,
                                              const int* __restrict__ col,
                                              uint* __restrict__ runtbl,
                                              uint* __restrict__ gseg) {
    __shared__ uint cnt[NG];   // per-group count (atomic rank source)
    __shared__ uint sc[NG];    // block-local exclusive scan
    __shared__ uint ss[256];   // scan workspace
    __shared__ uint pk[EPB];   // packed edges, ordered by group

    int b = blockIdx.x;
    int t = threadIdx.x;
    if (b < NBIN) {
        int e0 = b * EPB;
        int n = NE - e0; if (n > EPB) n = EPB;     // last block: 1069

        for (int i = t; i < NG; i += 256) cnt[i] = 0;
        __syncthreads();

        // load up to 5 edges/thread, coalesced
        int r[5], c[5], g[5];
        uint rk[5];
#pragma unroll
        for (int j = 0; j < 5; ++j) {
            int i = t + j * 256;
            int idx = (i < n) ? (e0 + i) : e0;     // clamped read
            r[j] = row[idx];
            c[j] = col[idx];
        }
#pragma unroll
        for (int j = 0; j < 5; ++j) {
            g[j] = r[j] >> 8;
            if (t + j * 256 < n) rk[j] = atomicAdd(&cnt[g[j]], 1u);
        }
        __syncthreads();

        // exclusive scan of cnt over 196 (padded to 256), Hillis-Steele
        ss[t] = (t < NG) ? cnt[t] : 0u;
        __syncthreads();
        for (int off = 1; off < 256; off <<= 1) {
            uint add = (t >= off) ? ss[t - off] : 0u;
            __syncthreads();
            ss[t] += add;
            __syncthreads();
        }
        if (t < NG) {
            sc[t] = ss[t] - cnt[t];
            // publish run descriptor: [g][b] = (local_start<<12)|len
            runtbl[(size_t)t * NBIN + b] = (sc[t] << 12) | cnt[t];
        }
        __syncthreads();

        // place edges into block-local group-ordered buffer (LDS scatter)
#pragma unroll
        for (int j = 0; j < 5; ++j) {
            if (t + j * 256 < n) {
                uint pos = sc[g[j]] + rk[j];
                pk[pos] = ((uint)(r[j] & 255) << 16) | (uint)(c[j] & 0xffff);
            }
        }
        __syncthreads();

        // identity copy-out: fully coalesced into this block's own region
        for (int i = t; i < n; i += 256)
            gseg[e0 + i] = pk[i];
    } else {
        int i = (b - NBIN) * 256 + t;              // 16384 elems exactly
        float v = W[i];
        ushort hh = f2bf(v);
        whi[i] = hh;
        wlo[i] = f2bf(v - bf2f((uint)hh));
    }
}

// ---------------- pass B: build CSR + deg/nrm + cast x -> xb SCALED by dis ----------
// 4 blocks per group; block handles 64 of the group's 256 rows.
// The cast is fused here (single read of x f32, single write of xb bf16),
// so the aggregation loop needs NO per-neighbor norm at all.
__global__ __launch_bounds__(256) void k_csr(const uint* __restrict__ gseg,
                                             const uint* __restrict__ runtbl,
                                             const float* __restrict__ x,
                                             uint* __restrict__ csr,
                                             int* __restrict__ deg_c,
                                             float* __restrict__ nrm,
                                             ushort* __restrict__ xb) {
    __shared__ ushort slots[64][62];
    __shared__ uint dcnt[64];
    __shared__ float sdis[64];
    __shared__ uint rt[NBIN];
    int g = blockIdx.x >> 2;
    int q = blockIdx.x & 3;
    int t = threadIdx.x;

    if (t < 64) dcnt[t] = 0;
    for (int i = t; i < NBIN; i += 256)
        rt[i] = runtbl[(size_t)g * NBIN + i];
    __syncthreads();

#pragma unroll
    for (int rep = 0; rep < NBIN / 256; ++rep) {
        int bb = t + rep * 256;
        uint d = rt[bb];
        uint s = d >> 12, len = d & 0xFFFu;
        const uint* p = gseg + (size_t)bb * EPB + s;
        for (uint k = 0; k < len; ++k) {
            uint e = p[k];
            int rl = (int)(e >> 16);               // row & 255
            if ((rl >> 6) == q) {
                int r6 = rl & 63;
                uint kk = atomicAdd(&dcnt[r6], 1u);
                if (kk < 62) slots[r6][kk] = (ushort)(e & 0xffff);
            }
        }
    }
    __syncthreads();

    int row0 = g * 256 + q * 64;
    // deg/nrm/dis for this block's 64 rows
    if (t < 64) {
        int rr = row0 + t;
        int d = (int)dcnt[t];
        float dis = (d > 0) ? rsqrtf((float)d) : 0.0f;
        sdis[t] = dis;
        if (rr < NN) {
            deg_c[rr] = d;
            nrm[rr] = dis;
        }
    }
    __syncthreads();
    // CSR write: 64 rows x 32 uints = 2048 uints, coalesced
    for (int i = t; i < 2048; i += 256) {
        int rl = i >> 5, w = i & 31;
        int rr = row0 + rl;
        if (rr < NN) {
            uint val;
            if (w == 0) val = dcnt[rl];
            else val = (uint)slots[rl][2 * w - 2] | ((uint)slots[rl][2 * w - 1] << 16);
            csr[(size_t)rr * RSTR + w] = val;
        }
    }
    // fused cast+scale: xb[rr] = bf16(x[rr] * dis[rr]); 64 rows x 32 float4
    for (int i = t; i < 2048; i += 256) {
        int rl = i >> 5, w = i & 31;               // w: float4 index in row
        int rr = row0 + rl;
        if (rr < NN) {
            float4 v = *(const float4*)(x + (size_t)rr * CH + w * 4);
            float s = sdis[rl];
            ushort4 o;
            o.x = f2bf(v.x * s); o.y = f2bf(v.y * s);
            o.z = f2bf(v.z * s); o.w = f2bf(v.w * s);
            *(ushort4*)(xb + (size_t)rr * CH + w * 4) = o;
        } else if (rr == NN) {                     // dedicated zero row for pad slots
            ushort4 o; o.x = 0; o.y = 0; o.z = 0; o.w = 0;
            *(ushort4*)(xb + (size_t)rr * CH + w * 4) = o;
        }
    }
}

// ---------------- fused aggregation + MFMA GEMM ----------------
// Block owns 32 nodes. Phase 1: each wave sums pre-scaled source rows for
// 8 nodes into an XOR-swizzled LDS A-tile. QUAD gather: each lane loads
// uint4 (16B); 64 lanes x 16B = 1024B = FOUR neighbor rows per VMEM instr
// (lane>>4 selects neighbor, lane&15 selects channel-octet). Pad slots
// read the zero row xb[NN]. Phase 2: 16x16x32 MFMA tile.
__global__ __launch_bounds__(256) void k_aggm(const ushort* __restrict__ xb,
                                              const int* __restrict__ deg_c,
                                              const float* __restrict__ nrm,
                                              const uint* __restrict__ csr,
                                              const ushort* __restrict__ whi,
                                              const ushort* __restrict__ wlo,
                                              const float* __restrict__ bias,
                                              float* __restrict__ out) {
    __shared__ ushort at[32 * 128];                // 8KB, swizzled
    const int wave = threadIdx.x >> 6;
    const int lane = threadIdx.x & 63;
    const int quad = lane >> 4;
    const int q1 = quad & 1, q2 = quad >> 1;
    const int ch0 = (lane & 15) * 8;               // ushort offset of this lane's octet
    const int m0 = blockIdx.x * 32;
    const int li = (lane < 62) ? lane : 0;

    // ---- phase 1: aggregate nodes m0+wave*8 .. +7 ----
    int node0 = m0 + wave * 8;
    int deg_n = 0; ushort craw_n = 0; float dr_n = 0.0f;
    if (node0 < NN) {
        deg_n  = deg_c[node0];
        craw_n = ((const ushort*)(csr + (size_t)node0 * RSTR))[2 + li];
        dr_n   = nrm[node0];
    }
    for (int s = 0; s < 8; ++s) {
        int node = node0 + s;
        int r = wave * 8 + s;
        if (node >= NN) {                          // zero the tile row (last block only)
            if (lane < 16) {
                int byte = (r * 256 + lane * 16) ^ ((r & 7) << 4);
                uint4 z; z.x = 0u; z.y = 0u; z.z = 0u; z.w = 0u;
                *(uint4*)((char*)at + byte) = z;
            }
            continue;
        }
        int deg = deg_n; ushort craw = craw_n; float dr = dr_n;
        int cli = (lane < deg) ? (int)craw : NN;   // pads -> zero row
        // prefetch next node's metadata under this node's gather loop
        int nxt = node + 1;
        if (s < 7 && nxt < NN) {
            deg_n  = deg_c[nxt];
            craw_n = ((const ushort*)(csr + (size_t)nxt * RSTR))[2 + li];
            dr_n   = nrm[nxt];
        }
        float a0 = 0.f, a1 = 0.f, a2 = 0.f, a3 = 0.f;
        float a4 = 0.f, a5 = 0.f, a6 = 0.f, a7 = 0.f;
        for (int j = 0; j < deg; j += 8) {
            // quad A: neighbors j..j+3
            int cA0 = __builtin_amdgcn_readlane(cli, j + 0);
            int cA1 = __builtin_amdgcn_readlane(cli, j + 1);
            int cA2 = __builtin_amdgcn_readlane(cli, j + 2);
            int cA3 = __builtin_amdgcn_readlane(cli, j + 3);
            int cA = q2 ? (q1 ? cA3 : cA2) : (q1 ? cA1 : cA0);
            const uint4 vA = *(const uint4*)(xb + (size_t)cA * CH + ch0);
            // quad B: neighbors j+4..j+7
            int cB0 = __builtin_amdgcn_readlane(cli, j + 4);
            int cB1 = __builtin_amdgcn_readlane(cli, j + 5);
            int cB2 = __builtin_amdgcn_readlane(cli, j + 6);
            int cB3 = __builtin_amdgcn_readlane(cli, j + 7);
            int cB = q2 ? (q1 ? cB3 : cB2) : (q1 ? cB1 : cB0);
            const uint4 vB = *(const uint4*)(xb + (size_t)cB * CH + ch0);

            a0 += bf2f(vA.x); a1 += __uint_as_float(vA.x & 0xffff0000u);
            a2 += bf2f(vA.y); a3 += __uint_as_float(vA.y & 0xffff0000u);
            a4 += bf2f(vA.z); a5 += __uint_as_float(vA.z & 0xffff0000u);
            a6 += bf2f(vA.w); a7 += __uint_as_float(vA.w & 0xffff0000u);

            a0 += bf2f(vB.x); a1 += __uint_as_float(vB.x & 0xffff0000u);
            a2 += bf2f(vB.y); a3 += __uint_as_float(vB.y & 0xffff0000u);
            a4 += bf2f(vB.z); a5 += __uint_as_float(vB.z & 0xffff0000u);
            a6 += bf2f(vB.w); a7 += __uint_as_float(vB.w & 0xffff0000u);
        }
        // reduce across the 4 quads (each holds partial sums for its neighbors)
        a0 += __shfl_xor(a0, 16); a0 += __shfl_xor(a0, 32);
        a1 += __shfl_xor(a1, 16); a1 += __shfl_xor(a1, 32);
        a2 += __shfl_xor(a2, 16); a2 += __shfl_xor(a2, 32);
        a3 += __shfl_xor(a3, 16); a3 += __shfl_xor(a3, 32);
        a4 += __shfl_xor(a4, 16); a4 += __shfl_xor(a4, 32);
        a5 += __shfl_xor(a5, 16); a5 += __shfl_xor(a5, 32);
        a6 += __shfl_xor(a6, 16); a6 += __shfl_xor(a6, 32);
        a7 += __shfl_xor(a7, 16); a7 += __shfl_xor(a7, 32);
        if (lane < 16) {
            uint4 wv;
            wv.x = (uint)f2bf(a0 * dr) | ((uint)f2bf(a1 * dr) << 16);
            wv.y = (uint)f2bf(a2 * dr) | ((uint)f2bf(a3 * dr) << 16);
            wv.z = (uint)f2bf(a4 * dr) | ((uint)f2bf(a5 * dr) << 16);
            wv.w = (uint)f2bf(a6 * dr) | ((uint)f2bf(a7 * dr) << 16);
            int byte = (r * 256 + lane * 16) ^ ((r & 7) << 4);
            *(uint4*)((char*)at + byte) = wv;
        }
    }
    __syncthreads();

    // ---- phase 2: GEMM out = A @ (Whi+Wlo)^T + b ----
    const int quad4 = lane >> 4;
    const int r16 = lane & 15;
    const int nt0 = wave * 2, nt1 = nt0 + 1;
    const ushort* bh0p = whi + (size_t)(nt0 * 16 + r16) * CH + quad4 * 8;
    const ushort* bl0p = wlo + (size_t)(nt0 * 16 + r16) * CH + quad4 * 8;
    const ushort* bh1p = whi + (size_t)(nt1 * 16 + r16) * CH + quad4 * 8;
    const ushort* bl1p = wlo + (size_t)(nt1 * 16 + r16) * CH + quad4 * 8;

    float b0 = bias[nt0 * 16 + r16];
    float b1 = bias[nt1 * 16 + r16];
    floatx4 acc00 = {b0, b0, b0, b0};
    floatx4 acc01 = {b1, b1, b1, b1};
    floatx4 acc10 = {b0, b0, b0, b0};
    floatx4 acc11 = {b1, b1, b1, b1};

    const int swz = (r16 & 7) << 4;                // (r16+16)&7 == r16&7
#pragma unroll
    for (int kb = 0; kb < 4; ++kb) {
        const int cb = quad4 * 16 + kb * 64;
        short8 A0 = *(const short8*)((const char*)at + ((r16 * 256 + cb) ^ swz));
        short8 A1 = *(const short8*)((const char*)at + (((r16 + 16) * 256 + cb) ^ swz));
        const int k0 = kb * 32;
        short8 h0 = *(const short8*)(bh0p + k0);
        short8 l0 = *(const short8*)(bl0p + k0);
        short8 h1 = *(const short8*)(bh1p + k0);
        short8 l1 = *(const short8*)(bl1p + k0);
        acc00 = __builtin_amdgcn_mfma_f32_16x16x32_bf16(A0, h0, acc00, 0, 0, 0);
        acc00 = __builtin_amdgcn_mfma_f32_16x16x32_bf16(A0, l0, acc00, 0, 0, 0);
        acc01 = __builtin_amdgcn_mfma_f32_16x16x32_bf16(A0, h1, acc01, 0, 0, 0);
        acc01 = __builtin_amdgcn_mfma_f32_16x16x32_bf16(A0, l1, acc01, 0, 0, 0);
        acc10 = __builtin_amdgcn_mfma_f32_16x16x32_bf16(A1, h0, acc10, 0, 0, 0);
        acc10 = __builtin_amdgcn_mfma_f32_16x16x32_bf16(A1, l0, acc10, 0, 0, 0);
        acc11 = __builtin_amdgcn_mfma_f32_16x16x32_bf16(A1, h1, acc11, 0, 0, 0);
        acc11 = __builtin_amdgcn_mfma_f32_16x16x32_bf16(A1, l1, acc11, 0, 0, 0);
    }

#pragma unroll
    for (int r = 0; r < 4; ++r) {
        int row0 = m0 + quad4 * 4 + r;
        int row1 = row0 + 16;
        if (row0 < NN) {
            out[(size_t)row0 * CH + nt0 * 16 + r16] = acc00[r];
            out[(size_t)row0 * CH + nt1 * 16 + r16] = acc01[r];
        }
        if (row1 < NN) {
            out[(size_t)row1 * CH + nt0 * 16 + r16] = acc10[r];
            out[(size_t)row1 * CH + nt1 * 16 + r16] = acc11[r];
        }
    }
}

extern "C" void kernel_launch(void* const* d_in, const int* in_sizes, int n_in,
                              void* d_out, int out_size, void* d_ws, size_t ws_size,
                              hipStream_t stream) {
    const float* x = (const float*)d_in[0];
    const int* ei = (const int*)d_in[1]; // [2, NE]: row = ei, col = ei + NE
    const float* W = (const float*)d_in[2];
    const float* b = (const float*)d_in[3];
    float* out = (float*)d_out;

    // ws: [csr NN*32 uint = 6.4MB][deg_c 50176 int][nrm 50176 f32]
    //     [xb (NN+1)*CH u16 (row NN = zero row)][whi 16384 u16][wlo 16384 u16]
    //     [runtbl NG*NBIN uint][gseg NBIN*EPB uint]
    uint* csr = (uint*)d_ws;
    int* deg_c = (int*)(csr + (size_t)NN * RSTR);
    float* nrm = (float*)(deg_c + 50176);
    ushort* xb = (ushort*)(nrm + 50176);
    ushort* whi = xb + (size_t)(NN + 1) * CH;
    ushort* wlo = whi + CH * CH;
    uint* runtbl = (uint*)(wlo + CH * CH);
    uint* gseg = runtbl + (size_t)NG * NBIN;

    k_prep<<<NBIN + 64, 256, 0, stream>>>(W, whi, wlo, ei, ei + NE, runtbl, gseg);
    k_csr<<<NG * 4, 256, 0, stream>>>(gseg, runtbl, x, csr, deg_c, nrm, xb);
    k_aggm<<<(NN + 31) / 32, 256, 0, stream>>>(xb, deg_c, nrm, csr, whi, wlo, b, out);
}

// Round 7
// 134.951 us; speedup vs baseline: 1.0713x; 1.0135x over previous
//
#include <hip/hip_runtime.h>
#include <hip/hip_bf16.h>

#define NN 50000
#define NE 625000
#define CH 128
// CSR row block: 32 uints = 128B = [u32 deg][62 ushort slots]; max degree ~38 << 62
#define RSTR 32
// counting-sort geometry: group = row >> 8 -> 196 groups of 256 rows
#define NG 196
#define NBIN 512           // sort blocks in pass A (deterministic, no device atomics)
#define EPB 1221           // edges per sort block (512*1221 = 625152 >= NE)

typedef __attribute__((ext_vector_type(8))) short short8;
typedef __attribute__((ext_vector_type(4))) float floatx4;
typedef __attribute__((ext_vector_type(2))) float f32x2;

__device__ __forceinline__ ushort f2bf(float v) {
    __hip_bfloat16 h = __float2bfloat16(v);
    return *(ushort*)&h;
}
__device__ __forceinline__ float bf2f(uint u) {
    return __uint_as_float(u << 16);
}
__device__ __forceinline__ f32x2 up2(uint u) {
    f32x2 r;
    r.x = __uint_as_float(u << 16);            // low bf16
    r.y = __uint_as_float(u & 0xffff0000u);    // high bf16
    return r;
}

// ---------------- prep: edge sort + W split ----------------
// blocks [0,512):    edge sort pass A: per-block group-sort into OWN gseg
//                    region (coalesced identity copy-out, zero device atomics)
// blocks [512,576):  W -> bf16 hi/lo split
__global__ __launch_bounds__(256) void k_prep(const float* __restrict__ W,
                                              ushort* __restrict__ whi,
                                              ushort* __restrict__ wlo,
                                              const int* __restrict__ row,
                                              const int* __restrict__ col,
                                              uint* __restrict__ runtbl,
                                              uint* __restrict__ gseg) {
    __shared__ uint cnt[NG];   // per-group count (atomic rank source)
    __shared__ uint sc[NG];    // block-local exclusive scan
    __shared__ uint ss[256];   // scan workspace
    __shared__ uint pk[EPB];   // packed edges, ordered by group

    int b = blockIdx.x;
    int t = threadIdx.x;
    if (b < NBIN) {
        int e0 = b * EPB;
        int n = NE - e0; if (n > EPB) n = EPB;     // last block: 1069

        for (int i = t; i < NG; i += 256) cnt[i] = 0;
        __syncthreads();

        // load up to 5 edges/thread, coalesced
        int r[5], c[5], g[5];
        uint rk[5];
#pragma unroll
        for (int j = 0; j < 5; ++j) {
            int i = t + j * 256;
            int idx = (i < n) ? (e0 + i) : e0;     // clamped read
            r[j] = row[idx];
            c[j] = col[idx];
        }
#pragma unroll
        for (int j = 0; j < 5; ++j) {
            g[j] = r[j] >> 8;
            if (t + j * 256 < n) rk[j] = atomicAdd(&cnt[g[j]], 1u);
        }
        __syncthreads();

        // exclusive scan of cnt over 196 (padded to 256), Hillis-Steele
        ss[t] = (t < NG) ? cnt[t] : 0u;
        __syncthreads();
        for (int off = 1; off < 256; off <<= 1) {
            uint add = (t >= off) ? ss[t - off] : 0u;
            __syncthreads();
            ss[t] += add;
            __syncthreads();
        }
        if (t < NG) {
            sc[t] = ss[t] - cnt[t];
            // publish run descriptor: [g][b] = (local_start<<12)|len
            runtbl[(size_t)t * NBIN + b] = (sc[t] << 12) | cnt[t];
        }
        __syncthreads();

        // place edges into block-local group-ordered buffer (LDS scatter)
#pragma unroll
        for (int j = 0; j < 5; ++j) {
            if (t + j * 256 < n) {
                uint pos = sc[g[j]] + rk[j];
                pk[pos] = ((uint)(r[j] & 255) << 16) | (uint)(c[j] & 0xffff);
            }
        }
        __syncthreads();

        // identity copy-out: fully coalesced into this block's own region
        for (int i = t; i < n; i += 256)
            gseg[e0 + i] = pk[i];
    } else {
        int i = (b - NBIN) * 256 + t;              // 16384 elems exactly
        float v = W[i];
        ushort hh = f2bf(v);
        whi[i] = hh;
        wlo[i] = f2bf(v - bf2f((uint)hh));
    }
}

// ---------------- pass B: build CSR + deg/nrm + cast x -> xb SCALED by dis ----------
// 4 blocks per group; block handles 64 of the group's 256 rows.
// The cast is fused here (single read of x f32, single write of xb bf16),
// so the aggregation loop needs NO per-neighbor norm at all.
__global__ __launch_bounds__(256) void k_csr(const uint* __restrict__ gseg,
                                             const uint* __restrict__ runtbl,
                                             const float* __restrict__ x,
                                             uint* __restrict__ csr,
                                             int* __restrict__ deg_c,
                                             float* __restrict__ nrm,
                                             ushort* __restrict__ xb) {
    __shared__ ushort slots[64][62];
    __shared__ uint dcnt[64];
    __shared__ float sdis[64];
    __shared__ uint rt[NBIN];
    int g = blockIdx.x >> 2;
    int q = blockIdx.x & 3;
    int t = threadIdx.x;

    if (t < 64) dcnt[t] = 0;
    for (int i = t; i < NBIN; i += 256)
        rt[i] = runtbl[(size_t)g * NBIN + i];
    __syncthreads();

#pragma unroll
    for (int rep = 0; rep < NBIN / 256; ++rep) {
        int bb = t + rep * 256;
        uint d = rt[bb];
        uint s = d >> 12, len = d & 0xFFFu;
        const uint* p = gseg + (size_t)bb * EPB + s;
        for (uint k = 0; k < len; ++k) {
            uint e = p[k];
            int rl = (int)(e >> 16);               // row & 255
            if ((rl >> 6) == q) {
                int r6 = rl & 63;
                uint kk = atomicAdd(&dcnt[r6], 1u);
                if (kk < 62) slots[r6][kk] = (ushort)(e & 0xffff);
            }
        }
    }
    __syncthreads();

    int row0 = g * 256 + q * 64;
    // deg/nrm/dis for this block's 64 rows
    if (t < 64) {
        int rr = row0 + t;
        int d = (int)dcnt[t];
        float dis = (d > 0) ? rsqrtf((float)d) : 0.0f;
        sdis[t] = dis;
        if (rr < NN) {
            deg_c[rr] = d;
            nrm[rr] = dis;
        }
    }
    __syncthreads();
    // CSR write: 64 rows x 32 uints = 2048 uints, coalesced
    for (int i = t; i < 2048; i += 256) {
        int rl = i >> 5, w = i & 31;
        int rr = row0 + rl;
        if (rr < NN) {
            uint val;
            if (w == 0) val = dcnt[rl];
            else val = (uint)slots[rl][2 * w - 2] | ((uint)slots[rl][2 * w - 1] << 16);
            csr[(size_t)rr * RSTR + w] = val;
        }
    }
    // fused cast+scale: xb[rr] = bf16(x[rr] * dis[rr]); 64 rows x 32 float4
    for (int i = t; i < 2048; i += 256) {
        int rl = i >> 5, w = i & 31;               // w: float4 index in row
        int rr = row0 + rl;
        if (rr < NN) {
            float4 v = *(const float4*)(x + (size_t)rr * CH + w * 4);
            float s = sdis[rl];
            ushort4 o;
            o.x = f2bf(v.x * s); o.y = f2bf(v.y * s);
            o.z = f2bf(v.z * s); o.w = f2bf(v.w * s);
            *(ushort4*)(xb + (size_t)rr * CH + w * 4) = o;
        } else if (rr == NN) {                     // dedicated zero row for pad slots
            ushort4 o; o.x = 0; o.y = 0; o.z = 0; o.w = 0;
            *(ushort4*)(xb + (size_t)rr * CH + w * 4) = o;
        }
    }
}

// ---------------- fused aggregation + MFMA GEMM ----------------
// Block owns 32 nodes. Phase 1: each wave sums pre-scaled source rows for
// 8 nodes into an XOR-swizzled LDS A-tile. QUAD gather: each lane loads
// uint4 (16B); 64 lanes x 16B = 1024B = FOUR neighbor rows per VMEM instr.
// Neighbor-index broadcast via 2 ds_bpermute/iter (replaces 8 readlane +
// select trees); accumulation in f32x2 -> v_pk_add_f32.
// Phase 2: 16x16x32 MFMA tile.
__global__ __launch_bounds__(256) void k_aggm(const ushort* __restrict__ xb,
                                              const int* __restrict__ deg_c,
                                              const float* __restrict__ nrm,
                                              const uint* __restrict__ csr,
                                              const ushort* __restrict__ whi,
                                              const ushort* __restrict__ wlo,
                                              const float* __restrict__ bias,
                                              float* __restrict__ out) {
    __shared__ ushort at[32 * 128];                // 8KB, swizzled
    const int wave = threadIdx.x >> 6;
    const int lane = threadIdx.x & 63;
    const int quad = lane >> 4;
    const int qb4 = quad * 4;                      // bpermute byte offset of this quad
    const int ch0 = (lane & 15) * 8;               // ushort offset of this lane's octet
    const int m0 = blockIdx.x * 32;
    const int li = (lane < 62) ? lane : 0;

    // ---- phase 1: aggregate nodes m0+wave*8 .. +7 ----
    int node0 = m0 + wave * 8;
    int deg_n = 0; ushort craw_n = 0; float dr_n = 0.0f;
    if (node0 < NN) {
        deg_n  = deg_c[node0];
        craw_n = ((const ushort*)(csr + (size_t)node0 * RSTR))[2 + li];
        dr_n   = nrm[node0];
    }
    for (int s = 0; s < 8; ++s) {
        int node = node0 + s;
        int r = wave * 8 + s;
        if (node >= NN) {                          // zero the tile row (last block only)
            if (lane < 16) {
                int byte = (r * 256 + lane * 16) ^ ((r & 7) << 4);
                uint4 z; z.x = 0u; z.y = 0u; z.z = 0u; z.w = 0u;
                *(uint4*)((char*)at + byte) = z;
            }
            continue;
        }
        int deg = deg_n; ushort craw = craw_n; float dr = dr_n;
        int cli = (lane < deg) ? (int)craw : NN;   // pads -> zero row
        // prefetch next node's metadata under this node's gather loop
        int nxt = node + 1;
        if (s < 7 && nxt < NN) {
            deg_n  = deg_c[nxt];
            craw_n = ((const ushort*)(csr + (size_t)nxt * RSTR))[2 + li];
            dr_n   = nrm[nxt];
        }
        f32x2 acc0 = {0.f, 0.f}, acc1 = {0.f, 0.f};
        f32x2 acc2 = {0.f, 0.f}, acc3 = {0.f, 0.f};
        for (int j = 0; j < deg; j += 8) {
            int idxA = j * 4 + qb4;                // lane (j+quad), byte index
            int idxB = idxA + 16;                  // lane (j+4+quad)
            int cA = __builtin_amdgcn_ds_bpermute(idxA, cli);
            int cB = __builtin_amdgcn_ds_bpermute(idxB, cli);
            const uint4 vA = *(const uint4*)(xb + (size_t)cA * CH + ch0);
            const uint4 vB = *(const uint4*)(xb + (size_t)cB * CH + ch0);
            acc0 += up2(vA.x); acc1 += up2(vA.y);
            acc2 += up2(vA.z); acc3 += up2(vA.w);
            acc0 += up2(vB.x); acc1 += up2(vB.y);
            acc2 += up2(vB.z); acc3 += up2(vB.w);
        }
        // reduce across the 4 quads (each holds partial sums for its neighbors)
        float a0 = acc0.x, a1 = acc0.y, a2 = acc1.x, a3 = acc1.y;
        float a4 = acc2.x, a5 = acc2.y, a6 = acc3.x, a7 = acc3.y;
        a0 += __shfl_xor(a0, 16); a0 += __shfl_xor(a0, 32);
        a1 += __shfl_xor(a1, 16); a1 += __shfl_xor(a1, 32);
        a2 += __shfl_xor(a2, 16); a2 += __shfl_xor(a2, 32);
        a3 += __shfl_xor(a3, 16); a3 += __shfl_xor(a3, 32);
        a4 += __shfl_xor(a4, 16); a4 += __shfl_xor(a4, 32);
        a5 += __shfl_xor(a5, 16); a5 += __shfl_xor(a5, 32);
        a6 += __shfl_xor(a6, 16); a6 += __shfl_xor(a6, 32);
        a7 += __shfl_xor(a7, 16); a7 += __shfl_xor(a7, 32);
        if (lane < 16) {
            uint4 wv;
            wv.x = (uint)f2bf(a0 * dr) | ((uint)f2bf(a1 * dr) << 16);
            wv.y = (uint)f2bf(a2 * dr) | ((uint)f2bf(a3 * dr) << 16);
            wv.z = (uint)f2bf(a4 * dr) | ((uint)f2bf(a5 * dr) << 16);
            wv.w = (uint)f2bf(a6 * dr) | ((uint)f2bf(a7 * dr) << 16);
            int byte = (r * 256 + lane * 16) ^ ((r & 7) << 4);
            *(uint4*)((char*)at + byte) = wv;
        }
    }
    __syncthreads();

    // ---- phase 2: GEMM out = A @ (Whi+Wlo)^T + b ----
    const int quad4 = lane >> 4;
    const int r16 = lane & 15;
    const int nt0 = wave * 2, nt1 = nt0 + 1;
    const ushort* bh0p = whi + (size_t)(nt0 * 16 + r16) * CH + quad4 * 8;
    const ushort* bl0p = wlo + (size_t)(nt0 * 16 + r16) * CH + quad4 * 8;
    const ushort* bh1p = whi + (size_t)(nt1 * 16 + r16) * CH + quad4 * 8;
    const ushort* bl1p = wlo + (size_t)(nt1 * 16 + r16) * CH + quad4 * 8;

    float b0 = bias[nt0 * 16 + r16];
    float b1 = bias[nt1 * 16 + r16];
    floatx4 acc00 = {b0, b0, b0, b0};
    floatx4 acc01 = {b1, b1, b1, b1};
    floatx4 acc10 = {b0, b0, b0, b0};
    floatx4 acc11 = {b1, b1, b1, b1};

    const int swz = (r16 & 7) << 4;                // (r16+16)&7 == r16&7
#pragma unroll
    for (int kb = 0; kb < 4; ++kb) {
        const int cb = quad4 * 16 + kb * 64;
        short8 A0 = *(const short8*)((const char*)at + ((r16 * 256 + cb) ^ swz));
        short8 A1 = *(const short8*)((const char*)at + (((r16 + 16) * 256 + cb) ^ swz));
        const int k0 = kb * 32;
        short8 h0 = *(const short8*)(bh0p + k0);
        short8 l0 = *(const short8*)(bl0p + k0);
        short8 h1 = *(const short8*)(bh1p + k0);
        short8 l1 = *(const short8*)(bl1p + k0);
        acc00 = __builtin_amdgcn_mfma_f32_16x16x32_bf16(A0, h0, acc00, 0, 0, 0);
        acc00 = __builtin_amdgcn_mfma_f32_16x16x32_bf16(A0, l0, acc00, 0, 0, 0);
        acc01 = __builtin_amdgcn_mfma_f32_16x16x32_bf16(A0, h1, acc01, 0, 0, 0);
        acc01 = __builtin_amdgcn_mfma_f32_16x16x32_bf16(A0, l1, acc01, 0, 0, 0);
        acc10 = __builtin_amdgcn_mfma_f32_16x16x32_bf16(A1, h0, acc10, 0, 0, 0);
        acc10 = __builtin_amdgcn_mfma_f32_16x16x32_bf16(A1, l0, acc10, 0, 0, 0);
        acc11 = __builtin_amdgcn_mfma_f32_16x16x32_bf16(A1, h1, acc11, 0, 0, 0);
        acc11 = __builtin_amdgcn_mfma_f32_16x16x32_bf16(A1, l1, acc11, 0, 0, 0);
    }

#pragma unroll
    for (int r = 0; r < 4; ++r) {
        int row0 = m0 + quad4 * 4 + r;
        int row1 = row0 + 16;
        if (row0 < NN) {
            out[(size_t)row0 * CH + nt0 * 16 + r16] = acc00[r];
            out[(size_t)row0 * CH + nt1 * 16 + r16] = acc01[r];
        }
        if (row1 < NN) {
            out[(size_t)row1 * CH + nt0 * 16 + r16] = acc10[r];
            out[(size_t)row1 * CH + nt1 * 16 + r16] = acc11[r];
        }
    }
}

extern "C" void kernel_launch(void* const* d_in, const int* in_sizes, int n_in,
                              void* d_out, int out_size, void* d_ws, size_t ws_size,
                              hipStream_t stream) {
    const float* x = (const float*)d_in[0];
    const int* ei = (const int*)d_in[1]; // [2, NE]: row = ei, col = ei + NE
    const float* W = (const float*)d_in[2];
    const float* b = (const float*)d_in[3];
    float* out = (float*)d_out;

    // ws: [csr NN*32 uint = 6.4MB][deg_c 50176 int][nrm 50176 f32]
    //     [xb (NN+1)*CH u16 (row NN = zero row)][whi 16384 u16][wlo 16384 u16]
    //     [runtbl NG*NBIN uint][gseg NBIN*EPB uint]
    uint* csr = (uint*)d_ws;
    int* deg_c = (int*)(csr + (size_t)NN * RSTR);
    float* nrm = (float*)(deg_c + 50176);
    ushort* xb = (ushort*)(nrm + 50176);
    ushort* whi = xb + (size_t)(NN + 1) * CH;
    ushort* wlo = whi + CH * CH;
    uint* runtbl = (uint*)(wlo + CH * CH);
    uint* gseg = runtbl + (size_t)NG * NBIN;

    k_prep<<<NBIN + 64, 256, 0, stream>>>(W, whi, wlo, ei, ei + NE, runtbl, gseg);
    k_csr<<<NG * 4, 256, 0, stream>>>(gseg, runtbl, x, csr, deg_c, nrm, xb);
    k_aggm<<<(NN + 31) / 32, 256, 0, stream>>>(xb, deg_c, nrm, csr, whi, wlo, b, out);
}